// Round 1
// baseline (285.101 us; speedup 1.0000x reference)
//
#include <hip/hip_runtime.h>
#include <hip/hip_bf16.h>
#include <math.h>

// MoE gate: B=524288 tokens, E=32, H=4, D=8, NE=64 experts, TOP_K=2.
// Everything up to expert_weight depends ONLY on taskID in [0,6) ->
// precompute clean_logits[6][64] and noise_std[6][64] once (kernel 1),
// then the per-token work is a pure streaming kernel (kernel 2), plus a
// deterministic tree reduction for `load` (kernel 3).

#define NE 64
#define NTASK 6
#define GRID_MAIN 1024            // blocks for the streaming kernel
#define BLOCK_MAIN 256            // 4 waves/block, 16 rows per block-iter

// ---------------------------------------------------------------------------
// Kernel 1: per-task tables. One block, 384 threads (6 waves = 6 tasks).
// ---------------------------------------------------------------------------
__global__ __launch_bounds__(384)
void moe_tables(const float* __restrict__ embed_table,
                const float* __restrict__ expert_keys,
                const float* __restrict__ Wq, const float* __restrict__ bq,
                const float* __restrict__ Wk, const float* __restrict__ bk,
                const float* __restrict__ Wg, const float* __restrict__ bg,
                const float* __restrict__ Wn, const float* __restrict__ bn,
                float* __restrict__ tbl /* [6][2][64]: clean, noise_std */)
{
    __shared__ float s_ek[1024];   // expert_keys 32x32
    __shared__ float s_wk[1024];   // Wk 32x32
    __shared__ float s_k[1024];    // k[s][e] = expert_keys @ Wk^T + bk (task-indep)
    __shared__ float s_q[NTASK][32];
    __shared__ float s_sc[NTASK][4][32];
    __shared__ float s_ew[NTASK][32];

    const int tid  = threadIdx.x;      // 0..383
    const int wave = tid >> 6;         // task id 0..5
    const int lane = tid & 63;

    for (int i = tid; i < 1024; i += 384) { s_ek[i] = expert_keys[i]; s_wk[i] = Wk[i]; }
    __syncthreads();

    // k = expert_keys @ Wk^T + bk  (shared by all tasks)
    for (int i = tid; i < 1024; i += 384) {
        int s = i >> 5, e = i & 31;
        float acc = bk[e];
        for (int j = 0; j < 32; ++j) acc += s_ek[s*32 + j] * s_wk[e*32 + j];
        s_k[i] = acc;
    }
    __syncthreads();

    // q_t = (embed[t] @ Wq^T + bq) * 1/sqrt(D)
    if (lane < 32) {
        float acc = bq[lane];
        for (int j = 0; j < 32; ++j) acc += embed_table[wave*32 + j] * Wq[lane*32 + j];
        s_q[wave][lane] = acc * 0.35355339059327373f;  // 1/sqrt(8)
    }
    __syncthreads();

    // scores[h][s] = sum_d q[h*8+d] * k[s][h*8+d]
    for (int r = lane; r < 128; r += 64) {
        int h = r >> 5, s = r & 31;
        float acc = 0.f;
        for (int d = 0; d < 8; ++d) acc += s_q[wave][h*8 + d] * s_k[s*32 + h*8 + d];
        s_sc[wave][h][s] = acc;
    }
    __syncthreads();

    // per-head softmax over the 32 experts
    if (lane < 4) {
        int h = lane;
        float m = -1e30f;
        for (int s = 0; s < 32; ++s) m = fmaxf(m, s_sc[wave][h][s]);
        float sum = 0.f;
        for (int s = 0; s < 32; ++s) { float e = expf(s_sc[wave][h][s] - m); s_sc[wave][h][s] = e; sum += e; }
        float inv = 1.f / sum;
        for (int s = 0; s < 32; ++s) s_sc[wave][h][s] *= inv;
    }
    __syncthreads();

    // mean over heads, softmax over experts -> expert_weight
    if (lane == 0) {
        float aw[32];
        float m = -1e30f;
        for (int s = 0; s < 32; ++s) {
            float a = 0.25f * (s_sc[wave][0][s] + s_sc[wave][1][s] +
                               s_sc[wave][2][s] + s_sc[wave][3][s]);
            aw[s] = a; m = fmaxf(m, a);
        }
        float sum = 0.f;
        for (int s = 0; s < 32; ++s) { float e = expf(aw[s] - m); aw[s] = e; sum += e; }
        float inv = 1.f / sum;
        for (int s = 0; s < 32; ++s) s_ew[wave][s] = aw[s] * inv;
    }
    __syncthreads();

    // clean_logits and noise_std per expert (64 outputs, one per lane)
    {
        int j = lane;   // 0..63
        float c = bg[j], n = bn[j];
        for (int s = 0; s < 32; ++s) {
            float w = s_ew[wave][s];
            c += w * Wg[j*32 + s];
            n += w * Wn[j*32 + s];
        }
        // softplus(x) = max(x,0) + log1p(exp(-|x|))
        float sp = fmaxf(n, 0.f) + log1pf(expf(-fabsf(n)));
        tbl[(wave*2    )*64 + j] = c;
        tbl[(wave*2 + 1)*64 + j] = sp + 0.01f;   // NOISE_EPS
    }
}

// ---------------------------------------------------------------------------
// Kernel 2: streaming gate kernel. Each wave handles 4 rows/iter; lane l owns
// 4 consecutive cols of row (l>>4) -> float4 loads/stores, fully coalesced.
// ---------------------------------------------------------------------------
__device__ __forceinline__ bool better(float v, int i, float V, int I) {
    // lexicographic: value desc, index asc (jax.lax.top_k tie rule)
    return (v > V) || (v == V && i < I);
}

__global__ __launch_bounds__(BLOCK_MAIN)
void moe_gate(const int* __restrict__ taskID,
              const float* __restrict__ noise,
              const float* __restrict__ tbl,
              float* __restrict__ gates,
              float* __restrict__ partials,
              int B)
{
    __shared__ float stbl[NTASK*2*64];   // 3 KiB: clean/std per task
    __shared__ float sload[NE];

    const int tid = threadIdx.x;
    for (int i = tid; i < NTASK*2*64; i += BLOCK_MAIN) stbl[i] = tbl[i];
    if (tid < NE) sload[tid] = 0.f;
    __syncthreads();

    const int wave = tid >> 6;        // 0..3
    const int lane = tid & 63;
    const int grp  = lane >> 4;       // row within wave's quad: 0..3
    const int gl   = lane & 15;       // lane within 16-lane row group
    const int c0   = gl * 4;          // first of 4 owned columns

    for (long rb = (long)blockIdx.x * 16; rb < B; rb += (long)gridDim.x * 16) {
        long row = rb + wave*4 + grp;
        if (row < B) {
            int t = taskID[row];
            const float* cl = &stbl[(t*2    )*64];
            const float* ns = &stbl[(t*2 + 1)*64];

            float4 nz = *(const float4*)(noise + row*64 + c0);
            float4 cc = *(const float4*)(cl + c0);
            float4 ss = *(const float4*)(ns + c0);

            float v[4];
            v[0] = cc.x + nz.x * ss.x;
            v[1] = cc.y + nz.y * ss.y;
            v[2] = cc.z + nz.z * ss.z;
            v[3] = cc.w + nz.w * ss.w;

            // local top-2 of 4 (indices ascending -> strict > keeps tie rule)
            float v1 = v[0]; int i1 = c0;
            float v2 = -1e30f; int i2 = 1 << 20;
            #pragma unroll
            for (int k = 1; k < 4; ++k) {
                if (v[k] > v1)      { v2 = v1; i2 = i1; v1 = v[k]; i1 = c0 + k; }
                else if (v[k] > v2) { v2 = v[k]; i2 = c0 + k; }
            }

            // merge across the 16-lane group (masks 1,2,4,8 stay in-group)
            #pragma unroll
            for (int m = 1; m < 16; m <<= 1) {
                float w1 = __shfl_xor(v1, m); int j1 = __shfl_xor(i1, m);
                float w2 = __shfl_xor(v2, m); int j2 = __shfl_xor(i2, m);
                if (better(w1, j1, v1, i1)) {
                    if (better(v1, i1, w2, j2)) { v2 = v1; i2 = i1; }
                    else                        { v2 = w2; i2 = j2; }
                    v1 = w1; i1 = j1;
                } else if (better(w1, j1, v2, i2)) {
                    v2 = w1; i2 = j1;
                }
            }

            // softmax over the two selected logits
            float e2  = expf(v2 - v1);
            float inv = 1.f / (1.f + e2);
            float g1  = inv, g2 = e2 * inv;

            float4 o;
            o.x = (c0     == i1) ? g1 : (c0     == i2) ? g2 : 0.f;
            o.y = (c0 + 1 == i1) ? g1 : (c0 + 1 == i2) ? g2 : 0.f;
            o.z = (c0 + 2 == i1) ? g1 : (c0 + 2 == i2) ? g2 : 0.f;
            o.w = (c0 + 3 == i1) ? g1 : (c0 + 3 == i2) ? g2 : 0.f;
            *(float4*)(gates + row*64 + c0) = o;

            if (gl == 0) {
                atomicAdd(&sload[i1], g1);
                atomicAdd(&sload[i2], g2);
            }
        }
    }
    __syncthreads();
    if (tid < NE) partials[(long)blockIdx.x * NE + tid] = sload[tid];
}

// ---------------------------------------------------------------------------
// Kernel 3: deterministic reduction of per-block partials -> load[64].
// ---------------------------------------------------------------------------
__global__ __launch_bounds__(1024)
void moe_load_reduce(const float* __restrict__ partials, float* __restrict__ load)
{
    __shared__ float s[1024];
    const int tid  = threadIdx.x;       // 0..1023
    const int bin  = tid & 63;
    const int part = tid >> 6;          // 0..15, each sums 64 partials
    float acc = 0.f;
    for (int p = part*64; p < part*64 + 64; ++p)
        acc += partials[(long)p * NE + bin];
    s[part*64 + bin] = acc;
    __syncthreads();
    if (tid < NE) {
        float a = 0.f;
        for (int p = 0; p < 16; ++p) a += s[p*64 + tid];
        load[tid] = a;
    }
}

// ---------------------------------------------------------------------------
extern "C" void kernel_launch(void* const* d_in, const int* in_sizes, int n_in,
                              void* d_out, int out_size, void* d_ws, size_t ws_size,
                              hipStream_t stream)
{
    const int*   taskID      = (const int*)  d_in[0];
    const float* noise       = (const float*)d_in[1];
    const float* embed_table = (const float*)d_in[2];
    const float* expert_keys = (const float*)d_in[3];
    const float* Wq          = (const float*)d_in[4];
    const float* bq          = (const float*)d_in[5];
    const float* Wk          = (const float*)d_in[6];
    const float* bk          = (const float*)d_in[7];
    const float* Wg          = (const float*)d_in[8];
    const float* bg          = (const float*)d_in[9];
    const float* Wn          = (const float*)d_in[10];
    const float* bn          = (const float*)d_in[11];

    const int B = in_sizes[0];                 // 524288

    float* gates = (float*)d_out;              // B*64
    float* load  = gates + (size_t)B * NE;     // 64

    float* tbl      = (float*)d_ws;                         // 768 floats
    float* partials = (float*)((char*)d_ws + 4096);         // GRID_MAIN*64 floats

    moe_tables<<<1, 384, 0, stream>>>(embed_table, expert_keys,
                                      Wq, bq, Wk, bk, Wg, bg, Wn, bn, tbl);
    moe_gate<<<GRID_MAIN, BLOCK_MAIN, 0, stream>>>(taskID, noise, tbl,
                                                   gates, partials, B);
    moe_load_reduce<<<1, 1024, 0, stream>>>(partials, load);
}